// Round 3
// baseline (3533.623 us; speedup 1.0000x reference)
//
#include <hip/hip_runtime.h>
#include <hip/hip_bf16.h>

// ---------------------------------------------------------------------------
// VQ-VAE pose: 15 pointwise GEMMs + VQ + MSE.
// Round 3: diagnosis/robustness round.
//  - Runtime input-dtype detection (fp32 vs bf16) -> weights converted to
//    fp32 in ws; first-GEMM load / last-GEMM store / diff store are
//    flag-branched.
//  - 4-way row chunking (everything is pointwise in T) -> ~67 MiB ws
//    footprint, robust to unknown ws_size.
//  - fp32 activations end-to-end (argmin fidelity).
// ---------------------------------------------------------------------------

#define NTOT 131072            // B*T
#define NC   4                 // row chunks
#define MC   (NTOT / NC)       // 32768 rows per chunk
#define EDIM 64
#define NEMB 512

// ---------------- dtype detection (fp32 vs bf16) ---------------------------
__global__ void detect_k(const void* __restrict__ x, int* __restrict__ flag,
                         float* __restrict__ acc)
{
    __shared__ int s_bad;
    if (threadIdx.x == 0) s_bad = 0;
    __syncthreads();
    const unsigned short* u = (const unsigned short*)x;
    int bad = 0;
    for (int i = threadIdx.x; i < 2048; i += 256) {
        unsigned short h = u[i];
        int ex = (h >> 7) & 0xFF;           // bf16 exponent field
        if (h != 0 && (ex < 100 || ex > 140)) bad++;   // implausible for N(0,1) bf16
    }
    atomicAdd(&s_bad, bad);
    __syncthreads();
    if (threadIdx.x == 0) { *flag = (s_bad > 256) ? 1 : 0; *acc = 0.f; }
}

// ---------------- convert all weights/biases/embed to fp32 -----------------
struct WTbl { const void* p[31]; int off[31]; int n[31]; };

__global__ void convw_k(WTbl t, float* __restrict__ dst, const int* __restrict__ flag)
{
    const bool f32 = (*flag != 0);
    const int ti = blockIdx.x;              // one block per tensor
    const void* src = t.p[ti];
    float* d = dst + t.off[ti];
    const int n = t.n[ti];
    for (int i = threadIdx.x; i < n; i += 256)
        d[i] = f32 ? ((const float*)src)[i]
                   : __bfloat162float(((const __hip_bfloat16*)src)[i]);
}

// ---------------- GEMM ------------------------------------------------------
// Y[M,O] = act((PRE?relu(X):X)[M,K] @ W[O,K]^T + b) (+R). 64x64 tile, BK=32.
// XM: 0=fp32 buffer, 2=dynamic (d_in[0]).  YM: 0=fp32 buffer, 1=dynamic (d_out).
template <int XM>
static __device__ __forceinline__ float ldx(const void* p, size_t i, bool f32d)
{
    if (XM == 0) return ((const float*)p)[i];
    return f32d ? ((const float*)p)[i]
                : __bfloat162float(((const __hip_bfloat16*)p)[i]);
}

template <bool PRE_RELU, bool POST_RELU, bool RES, int XM, int YM>
__global__ __launch_bounds__(256)
void gemm_k(const void* __restrict__ X, size_t xoff,
            const float* __restrict__ W, const float* __restrict__ Bv,
            const float* R, void* Y, size_t yoff,
            int M, int K, int O, const int* __restrict__ dtf)
{
    __shared__ float Xs[32][68];
    __shared__ float Ws[32][68];

    const bool f32d = (XM == 2 || YM == 1) ? (*dtf != 0) : false;

    const int tid = threadIdx.x;
    const int tx  = tid & 15;
    const int ty  = tid >> 4;
    const int m0  = blockIdx.x * 64;
    const int o0  = blockIdx.y * 64;

    float acc[4][4] = {};

    const int KC = (K + 31) >> 5;
    for (int kc = 0; kc < KC; ++kc) {
        const int k0 = kc << 5;
        #pragma unroll
        for (int l = 0; l < 8; ++l) {
            int e  = tid + l * 256;
            int kk = e & 31, m = e >> 5;
            int kg = k0 + kk;
            float v = 0.f;
            if (kg < K) v = ldx<XM>(X, xoff + (size_t)(m0 + m) * K + kg, f32d);
            if (PRE_RELU) v = fmaxf(v, 0.f);
            Xs[kk][m] = v;
        }
        #pragma unroll
        for (int l = 0; l < 8; ++l) {
            int e  = tid + l * 256;
            int kk = e & 31, o = e >> 5;
            int kg = k0 + kk, og = o0 + o;
            Ws[kk][o] = (kg < K && og < O) ? W[(size_t)og * K + kg] : 0.f;
        }
        __syncthreads();
        #pragma unroll
        for (int kk = 0; kk < 32; ++kk) {
            float a[4], b[4];
            *(float4*)a = *(const float4*)&Xs[kk][ty * 4];
            *(float4*)b = *(const float4*)&Ws[kk][tx * 4];
            #pragma unroll
            for (int i = 0; i < 4; ++i)
                #pragma unroll
                for (int j = 0; j < 4; ++j)
                    acc[i][j] = fmaf(a[i], b[j], acc[i][j]);
        }
        __syncthreads();
    }

    #pragma unroll
    for (int j = 0; j < 4; ++j) {
        int c = o0 + tx * 4 + j;
        if (c >= O) continue;
        float bb = Bv[c];
        #pragma unroll
        for (int i = 0; i < 4; ++i) {
            int r = m0 + ty * 4 + i;
            float v = acc[i][j] + bb;
            if (RES) v += R[(size_t)r * O + c];
            if (POST_RELU) v = fmaxf(v, 0.f);
            size_t yi = yoff + (size_t)r * O + c;
            if (YM == 0)      ((float*)Y)[yi] = v;
            else if (f32d)    ((float*)Y)[yi] = v;
            else              ((__hip_bfloat16*)Y)[yi] = __float2bfloat16(v);
        }
    }
}

// ---------------- codebook prep --------------------------------------------
__global__ void prep_k(const float* __restrict__ E, float* __restrict__ Et)
{
    int idx = blockIdx.x * 256 + threadIdx.x;   // 0..32767; E is [64][512]
    Et[(idx & 511) * EDIM + (idx >> 9)] = E[idx];
}

__global__ void e2_k(const float* __restrict__ Et, float* __restrict__ e2)
{
    int e = blockIdx.x * 256 + threadIdx.x;     // 0..511
    float s = 0.f;
    #pragma unroll
    for (int d = 0; d < EDIM; ++d) { float v = Et[e * EDIM + d]; s = fmaf(v, v, s); }
    e2[e] = s;
}

// ---------------- VQ: one thread per row -----------------------------------
__global__ __launch_bounds__(256, 2)
void vq_k(const float* __restrict__ Z, const float* __restrict__ Et,
          const float* __restrict__ e2, float* __restrict__ Q,
          float* __restrict__ acc)
{
    const int r = blockIdx.x * 256 + threadIdx.x;
    float z[EDIM];
    #pragma unroll
    for (int d = 0; d < EDIM; ++d) z[d] = Z[(size_t)r * EDIM + d];

    float best = 3.4e38f;
    int   bi   = 0;
    for (int e = 0; e < NEMB; ++e) {
        const float* er = Et + e * EDIM;        // wave-uniform -> scalar loads
        float dot = 0.f;
        #pragma unroll
        for (int d = 0; d < EDIM; ++d) dot = fmaf(z[d], er[d], dot);
        float s = fmaf(-2.f, dot, e2[e]);
        if (s < best) { best = s; bi = e; }     // first-min == np.argmin
    }

    const float* eb = Et + bi * EDIM;
    float ds = 0.f;
    #pragma unroll
    for (int d = 0; d < EDIM; ++d) {
        float q = eb[d];
        Q[(size_t)r * EDIM + d] = q;            // fp32 codes, exact
        float t = q - z[d];
        ds = fmaf(t, t, ds);
    }
    #pragma unroll
    for (int off = 32; off; off >>= 1) ds += __shfl_down(ds, off);
    if ((threadIdx.x & 63) == 0) atomicAdd(acc, ds);
}

__global__ void diff_k(const float* __restrict__ acc, void* __restrict__ out,
                       size_t off, const int* __restrict__ dtf)
{
    if (threadIdx.x == 0) {
        float v = *acc * (1.0f / 8388608.0f);   // /(32*4096*64)
        if (*dtf) ((float*)out)[off] = v;
        else      ((__hip_bfloat16*)out)[off] = __float2bfloat16(v);
    }
}

// ---------------------------------------------------------------------------
extern "C" void kernel_launch(void* const* d_in, const int* in_sizes, int n_in,
                              void* d_out, int out_size, void* d_ws, size_t ws_size,
                              hipStream_t stream)
{
    // ---- workspace layout (~67 MiB total) ----
    char* ws = (char*)d_ws;
    float* A1  = (float*)ws;                         // MC x 256 fp32 (32 MiB)
    float* A2  = (float*)(ws + 33554432);            // MC x 256 fp32 (32 MiB)
    float* Wf  = (float*)(ws + 67108864);            // fp32 weights (~1.3 MiB)
    float* Et  = (float*)(ws + 69206016);            // 512 x 64
    float* e2  = Et + NEMB * EDIM;                   // 512
    float* acc = e2 + NEMB;                          // 1
    int*   dtf = (int*)(acc + 1);                    // dtype flag

    // weight table: d_in[1..31] -> fp32 at Wf + off
    WTbl t;
    int off[32];
    int cum = 0;
    for (int i = 1; i < 32; ++i) {
        t.p[i - 1]   = d_in[i];
        t.off[i - 1] = cum;
        t.n[i - 1]   = in_sizes[i];
        off[i] = cum;
        cum += in_sizes[i];
    }
    const float* W_ew0 = Wf + off[1],  *B_ew0 = Wf + off[2];
    const float* W_ew1 = Wf + off[3],  *B_ew1 = Wf + off[4];
    const float* W_ew2 = Wf + off[5],  *B_ew2 = Wf + off[6];
    const float* W_r0a = Wf + off[7],  *B_r0a = Wf + off[8];
    const float* W_r0b = Wf + off[9],  *B_r0b = Wf + off[10];
    const float* W_r1a = Wf + off[11], *B_r1a = Wf + off[12];
    const float* W_r1b = Wf + off[13], *B_r1b = Wf + off[14];
    const float* W_qc  = Wf + off[15], *B_qc  = Wf + off[16];
    const float* Emb   = Wf + off[17];
    const float* W_d0  = Wf + off[18], *B_d0  = Wf + off[19];
    const float* W_s0a = Wf + off[20], *B_s0a = Wf + off[21];
    const float* W_s0b = Wf + off[22], *B_s0b = Wf + off[23];
    const float* W_s1a = Wf + off[24], *B_s1a = Wf + off[25];
    const float* W_s1b = Wf + off[26], *B_s1b = Wf + off[27];
    const float* W_d1  = Wf + off[28], *B_d1  = Wf + off[29];
    const float* W_d2  = Wf + off[30], *B_d2  = Wf + off[31];

    dim3 blk(256);
    auto g = [](int o) { return dim3(MC / 64, (o + 63) / 64); };
    const float* nf = nullptr;

    detect_k<<<1, blk, 0, stream>>>(d_in[0], dtf, acc);
    convw_k<<<31, blk, 0, stream>>>(t, Wf, dtf);
    prep_k<<<128, blk, 0, stream>>>(Emb, Et);
    e2_k<<<2, blk, 0, stream>>>(Et, e2);

    for (int c = 0; c < NC; ++c) {
        const size_t r0 = (size_t)c * MC;
        // ---- encoder ----
        gemm_k<false, true,  false, 2, 0><<<g(128), blk, 0, stream>>>(d_in[0], r0 * 165, W_ew0, B_ew0, nf, A1, 0, MC, 165, 128, dtf);
        gemm_k<false, true,  false, 0, 0><<<g(256), blk, 0, stream>>>(A1, 0, W_ew1, B_ew1, nf, A2, 0, MC, 128, 256, dtf);
        gemm_k<false, false, false, 0, 0><<<g(256), blk, 0, stream>>>(A2, 0, W_ew2, B_ew2, nf, A1, 0, MC, 256, 256, dtf);
        gemm_k<true,  true,  false, 0, 0><<<g(32),  blk, 0, stream>>>(A1, 0, W_r0a, B_r0a, nf, A2, 0, MC, 256, 32, dtf);
        gemm_k<false, false, true,  0, 0><<<g(256), blk, 0, stream>>>(A2, 0, W_r0b, B_r0b, A1, A1, 0, MC, 32, 256, dtf);
        gemm_k<true,  true,  false, 0, 0><<<g(32),  blk, 0, stream>>>(A1, 0, W_r1a, B_r1a, nf, A2, 0, MC, 256, 32, dtf);
        gemm_k<false, false, true,  0, 0><<<g(256), blk, 0, stream>>>(A2, 0, W_r1b, B_r1b, A1, A1, 0, MC, 32, 256, dtf);
        gemm_k<true,  false, false, 0, 0><<<g(64),  blk, 0, stream>>>(A1, 0, W_qc,  B_qc,  nf, A2, 0, MC, 256, 64, dtf);
        // ---- VQ (Z in A2 head, fp32 Q into A1 head) ----
        vq_k<<<MC / 256, blk, 0, stream>>>(A2, Et, e2, A1, acc);
        // ---- decoder ----
        gemm_k<false, false, false, 0, 0><<<g(256), blk, 0, stream>>>(A1, 0, W_d0,  B_d0,  nf, A2, 0, MC, 64,  256, dtf);
        gemm_k<true,  true,  false, 0, 0><<<g(32),  blk, 0, stream>>>(A2, 0, W_s0a, B_s0a, nf, A1, 0, MC, 256, 32, dtf);
        gemm_k<false, false, true,  0, 0><<<g(256), blk, 0, stream>>>(A1, 0, W_s0b, B_s0b, A2, A2, 0, MC, 32,  256, dtf);
        gemm_k<true,  true,  false, 0, 0><<<g(32),  blk, 0, stream>>>(A2, 0, W_s1a, B_s1a, nf, A1, 0, MC, 256, 32, dtf);
        gemm_k<false, false, true,  0, 0><<<g(256), blk, 0, stream>>>(A1, 0, W_s1b, B_s1b, A2, A2, 0, MC, 32,  256, dtf);
        gemm_k<true,  true,  false, 0, 0><<<g(128), blk, 0, stream>>>(A2, 0, W_d1,  B_d1,  nf, A1, 0, MC, 256, 128, dtf);
        gemm_k<false, false, false, 0, 1><<<g(165), blk, 0, stream>>>(A1, 0, W_d2,  B_d2,  nf, d_out, r0 * 165, MC, 128, 165, dtf);
    }

    diff_k<<<1, 64, 0, stream>>>(acc, d_out, (size_t)NTOT * 165, dtf);
}

// Round 4
// 3221.271 us; speedup vs baseline: 1.0970x; 1.0970x over previous
//
#include <hip/hip_runtime.h>
#include <hip/hip_bf16.h>

// ---------------------------------------------------------------------------
// VQ-VAE pose: 15 pointwise GEMMs + VQ + MSE.
// Round 4:
//  - vq_k rewritten: full-N single launch, 4-way code split per row across
//    lanes (shfl_xor min-combine, first-index tie-break), 2-way code unroll,
//    in-place Z->Q. Fixes 5.8% occupancy / 13% VALUBusy.
//  - GEMM: 128x64 tile, 8x4 per-thread (32 FMA per 3 ds_read_b128),
//    float4 staging + stores where K%4==0.
//  - Chunk count chosen at runtime from ws_size (deterministic per call).
//  - fp32 everywhere (round 3: absmax 9.8e-4, argmin exact).
// ---------------------------------------------------------------------------

#define NTOT 131072            // B*T
#define EDIM 64
#define NEMB 512

// ---------------- dtype detection (fp32 vs bf16) ---------------------------
__global__ void detect_k(const void* __restrict__ x, int* __restrict__ flag,
                         float* __restrict__ acc)
{
    __shared__ int s_bad;
    if (threadIdx.x == 0) s_bad = 0;
    __syncthreads();
    const unsigned short* u = (const unsigned short*)x;
    int bad = 0;
    for (int i = threadIdx.x; i < 2048; i += 256) {
        unsigned short h = u[i];
        int ex = (h >> 7) & 0xFF;
        if (h != 0 && (ex < 100 || ex > 140)) bad++;
    }
    atomicAdd(&s_bad, bad);
    __syncthreads();
    if (threadIdx.x == 0) { *flag = (s_bad > 256) ? 1 : 0; *acc = 0.f; }
}

// ---------------- convert weights/biases/embed to fp32 ---------------------
struct WTbl { const void* p[31]; int off[31]; int n[31]; };

__global__ void convw_k(WTbl t, float* __restrict__ dst, const int* __restrict__ flag)
{
    const bool f32 = (*flag != 0);
    const int ti = blockIdx.x;
    const void* src = t.p[ti];
    float* d = dst + t.off[ti];
    const int n = t.n[ti];
    for (int i = threadIdx.x; i < n; i += 256)
        d[i] = f32 ? ((const float*)src)[i]
                   : __bfloat162float(((const __hip_bfloat16*)src)[i]);
}

// ---------------- GEMM ------------------------------------------------------
// Y[M,O] = act((PRE?relu(X):X)[M,K] @ W[O,K]^T + b) (+R).
// 128x64 tile, BK=32, 8x4 per-thread.
// XM: 0=fp32 buffer, 2=dynamic (d_in[0]).  YM: 0=fp32 buffer, 1=dynamic (d_out).
template <int XM>
static __device__ __forceinline__ float ldx(const void* p, size_t i, bool f32d)
{
    if (XM == 0) return ((const float*)p)[i];
    return f32d ? ((const float*)p)[i]
                : __bfloat162float(((const __hip_bfloat16*)p)[i]);
}

template <bool PRE_RELU, bool POST_RELU, bool RES, int XM, int YM>
__global__ __launch_bounds__(256)
void gemm_k(const void* __restrict__ X, size_t xoff,
            const float* __restrict__ W, const float* __restrict__ Bv,
            const float* __restrict__ R, void* __restrict__ Y, size_t yoff,
            int M, int K, int O, const int* __restrict__ dtf)
{
    __shared__ float Xs[32][132];   // [k][m], 128 + 4 pad
    __shared__ float Ws[32][68];    // [k][o], 64 + 4 pad

    const bool f32d = (XM == 2 || YM == 1) ? (*dtf != 0) : false;

    const int tid = threadIdx.x;
    const int tx  = tid & 15;       // -> 4 cols
    const int ty  = tid >> 4;       // -> 8 rows
    const int m0  = blockIdx.x * 128;
    const int o0  = blockIdx.y * 64;

    float acc[8][4] = {};

    const int KC = (K + 31) >> 5;
    for (int kc = 0; kc < KC; ++kc) {
        const int k0 = kc << 5;
        // ---- stage X (128 x 32), pre-ReLU fused ----
        if (XM == 0 && (K & 3) == 0) {
            #pragma unroll
            for (int it = 0; it < 4; ++it) {
                int idx = tid + it * 256;          // 1024 float4 slots
                int kq = idx & 7, m = idx >> 3;
                int kg = k0 + kq * 4;
                float4 v = make_float4(0.f, 0.f, 0.f, 0.f);
                if (kg < K)
                    v = *(const float4*)((const float*)X + xoff + (size_t)(m0 + m) * K + kg);
                if (PRE_RELU) {
                    v.x = fmaxf(v.x, 0.f); v.y = fmaxf(v.y, 0.f);
                    v.z = fmaxf(v.z, 0.f); v.w = fmaxf(v.w, 0.f);
                }
                Xs[kq * 4 + 0][m] = v.x; Xs[kq * 4 + 1][m] = v.y;
                Xs[kq * 4 + 2][m] = v.z; Xs[kq * 4 + 3][m] = v.w;
            }
        } else {
            #pragma unroll
            for (int it = 0; it < 16; ++it) {
                int e = tid + it * 256;            // 4096 scalar slots
                int kk = e & 31, m = e >> 5;
                int kg = k0 + kk;
                float v = 0.f;
                if (kg < K) v = ldx<XM>(X, xoff + (size_t)(m0 + m) * K + kg, f32d);
                if (PRE_RELU) v = fmaxf(v, 0.f);
                Xs[kk][m] = v;
            }
        }
        // ---- stage W (64 x 32) ----
        if ((K & 3) == 0) {
            #pragma unroll
            for (int it = 0; it < 2; ++it) {
                int idx = tid + it * 256;          // 512 float4 slots
                int kq = idx & 7, o = idx >> 3;
                int kg = k0 + kq * 4, og = o0 + o;
                float4 v = make_float4(0.f, 0.f, 0.f, 0.f);
                if (kg < K && og < O)
                    v = *(const float4*)(W + (size_t)og * K + kg);
                Ws[kq * 4 + 0][o] = v.x; Ws[kq * 4 + 1][o] = v.y;
                Ws[kq * 4 + 2][o] = v.z; Ws[kq * 4 + 3][o] = v.w;
            }
        } else {
            #pragma unroll
            for (int it = 0; it < 8; ++it) {
                int e = tid + it * 256;            // 2048 scalar slots
                int kk = e & 31, o = e >> 5;
                int kg = k0 + kk, og = o0 + o;
                Ws[kk][o] = (kg < K && og < O) ? W[(size_t)og * K + kg] : 0.f;
            }
        }
        __syncthreads();
        // ---- compute ----
        #pragma unroll
        for (int kk = 0; kk < 32; ++kk) {
            float a[8], b[4];
            *(float4*)&a[0] = *(const float4*)&Xs[kk][ty * 8];
            *(float4*)&a[4] = *(const float4*)&Xs[kk][ty * 8 + 4];
            *(float4*)&b[0] = *(const float4*)&Ws[kk][tx * 4];
            #pragma unroll
            for (int i = 0; i < 8; ++i)
                #pragma unroll
                for (int j = 0; j < 4; ++j)
                    acc[i][j] = fmaf(a[i], b[j], acc[i][j]);
        }
        __syncthreads();
    }

    // ---- epilogue ----
    if (YM == 0 && (o0 + 64 <= O)) {
        // full-tile vectorized fp32 path
        const int c0 = o0 + tx * 4;
        float4 bb = *(const float4*)(Bv + c0);
        #pragma unroll
        for (int i = 0; i < 8; ++i) {
            int r = m0 + ty * 8 + i;
            float4 v;
            v.x = acc[i][0] + bb.x; v.y = acc[i][1] + bb.y;
            v.z = acc[i][2] + bb.z; v.w = acc[i][3] + bb.w;
            if (RES) {
                float4 rv = *(const float4*)(R + (size_t)r * O + c0);
                v.x += rv.x; v.y += rv.y; v.z += rv.z; v.w += rv.w;
            }
            if (POST_RELU) {
                v.x = fmaxf(v.x, 0.f); v.y = fmaxf(v.y, 0.f);
                v.z = fmaxf(v.z, 0.f); v.w = fmaxf(v.w, 0.f);
            }
            *(float4*)((float*)Y + yoff + (size_t)r * O + c0) = v;
        }
    } else {
        #pragma unroll
        for (int j = 0; j < 4; ++j) {
            int c = o0 + tx * 4 + j;
            if (c >= O) continue;
            float bb = Bv[c];
            #pragma unroll
            for (int i = 0; i < 8; ++i) {
                int r = m0 + ty * 8 + i;
                float v = acc[i][j] + bb;
                if (RES) v += R[(size_t)r * O + c];
                if (POST_RELU) v = fmaxf(v, 0.f);
                size_t yi = yoff + (size_t)r * O + c;
                if (YM == 0)   ((float*)Y)[yi] = v;
                else if (f32d) ((float*)Y)[yi] = v;
                else           ((__hip_bfloat16*)Y)[yi] = __float2bfloat16(v);
            }
        }
    }
}

// ---------------- codebook prep --------------------------------------------
__global__ void prep_k(const float* __restrict__ E, float* __restrict__ Et)
{
    int idx = blockIdx.x * 256 + threadIdx.x;   // E is [64][512]
    Et[(idx & 511) * EDIM + (idx >> 9)] = E[idx];
}

__global__ void e2_k(const float* __restrict__ Et, float* __restrict__ e2)
{
    int e = blockIdx.x * 256 + threadIdx.x;
    float s = 0.f;
    #pragma unroll
    for (int d = 0; d < EDIM; ++d) { float v = Et[e * EDIM + d]; s = fmaf(v, v, s); }
    e2[e] = s;
}

// ---------------- VQ: 4 lanes per row (code quarters), in-place Z->Q -------
__global__ __launch_bounds__(256)
void vq_k(float* __restrict__ Zq, const float* __restrict__ Et,
          const float* __restrict__ e2, float* __restrict__ acc)
{
    const int tid  = threadIdx.x;
    const int lane = tid & 63;
    const int w    = tid >> 6;
    const int rlo  = lane & 15;
    const int q    = lane >> 4;                 // code quarter
    const int r    = blockIdx.x * 64 + w * 16 + rlo;

    float z[64];
    const float* zp = Zq + (size_t)r * 64;
    #pragma unroll
    for (int d4 = 0; d4 < 16; ++d4)
        *(float4*)&z[d4 * 4] = *(const float4*)(zp + d4 * 4);

    float best = 3.4e38f;
    int   bi   = 0x7fffffff;
    const int e0 = q * 128;
    for (int e = e0; e < e0 + 128; e += 2) {
        const float* er0 = Et + (size_t)e * 64;
        const float* er1 = er0 + 64;
        float d0 = 0.f, d1 = 0.f;
        #pragma unroll
        for (int d = 0; d < 64; ++d) {
            d0 = fmaf(z[d], er0[d], d0);
            d1 = fmaf(z[d], er1[d], d1);
        }
        float s0 = fmaf(-2.f, d0, e2[e]);
        float s1 = fmaf(-2.f, d1, e2[e + 1]);
        if (s0 < best) { best = s0; bi = e; }      // ascending scan: first-min
        if (s1 < best) { best = s1; bi = e + 1; }
    }
    // min-combine across quarters (xor butterfly; ties -> lower index = np)
    {
        float ob = __shfl_xor(best, 16); int obi = __shfl_xor(bi, 16);
        if (ob < best || (ob == best && obi < bi)) { best = ob; bi = obi; }
        ob = __shfl_xor(best, 32); obi = __shfl_xor(bi, 32);
        if (ob < best || (ob == best && obi < bi)) { best = ob; bi = obi; }
    }
    // write this lane's quarter of Q; accumulate partial MSE
    const float* eb = Et + (size_t)bi * 64;
    float ds = 0.f;
    #pragma unroll
    for (int d4 = 0; d4 < 4; ++d4) {
        int d = q * 16 + d4 * 4;
        float4 qv = *(const float4*)(eb + d);
        float t;
        t = qv.x - z[d];     ds = fmaf(t, t, ds);
        t = qv.y - z[d + 1]; ds = fmaf(t, t, ds);
        t = qv.z - z[d + 2]; ds = fmaf(t, t, ds);
        t = qv.w - z[d + 3]; ds = fmaf(t, t, ds);
        *(float4*)(Zq + (size_t)r * 64 + d) = qv;
    }
    #pragma unroll
    for (int off = 32; off; off >>= 1) ds += __shfl_down(ds, off);
    if (lane == 0) atomicAdd(acc, ds);
}

__global__ void diff_k(const float* __restrict__ acc, void* __restrict__ out,
                       size_t off, const int* __restrict__ dtf)
{
    if (threadIdx.x == 0) {
        float v = *acc * (1.0f / 8388608.0f);   // /(32*4096*64)
        if (*dtf) ((float*)out)[off] = v;
        else      ((__hip_bfloat16*)out)[off] = __float2bfloat16(v);
    }
}

// ---------------------------------------------------------------------------
extern "C" void kernel_launch(void* const* d_in, const int* in_sizes, int n_in,
                              void* d_out, int out_size, void* d_ws, size_t ws_size,
                              hipStream_t stream)
{
    // ---- runtime chunk count from ws_size (deterministic across calls) ----
    // need = 32MiB (Zq) + 2*S (ping-pong) + ~6MiB (weights+codebook+pad)
    int NC;
    const size_t MB = 1048576;
    if      (ws_size >= 300 * MB) NC = 1;
    else if (ws_size >= 172 * MB) NC = 2;
    else if (ws_size >= 108 * MB) NC = 4;
    else if (ws_size >=  76 * MB) NC = 8;
    else                          NC = 16;
    const int MCr = NTOT / NC;
    const size_t S = (size_t)MCr * 256 * 4;

    char* ws = (char*)d_ws;
    float* Zq  = (float*)ws;                         // N x 64 fp32 (32 MiB)
    float* A1  = (float*)(ws + 32 * MB);
    float* A2  = (float*)(ws + 32 * MB + S);
    float* Wf  = (float*)(ws + 32 * MB + 2 * S);
    float* Et  = (float*)(ws + 32 * MB + 2 * S + 2 * MB);
    float* e2  = Et + NEMB * EDIM;
    float* acc = e2 + NEMB;
    int*   dtf = (int*)(acc + 1);

    // weight table: d_in[1..31] -> fp32 at Wf + off
    WTbl t;
    int off[32];
    int cum = 0;
    for (int i = 1; i < 32; ++i) {
        t.p[i - 1]   = d_in[i];
        t.off[i - 1] = cum;
        t.n[i - 1]   = in_sizes[i];
        off[i] = cum;
        cum += in_sizes[i];
    }
    const float* W_ew0 = Wf + off[1],  *B_ew0 = Wf + off[2];
    const float* W_ew1 = Wf + off[3],  *B_ew1 = Wf + off[4];
    const float* W_ew2 = Wf + off[5],  *B_ew2 = Wf + off[6];
    const float* W_r0a = Wf + off[7],  *B_r0a = Wf + off[8];
    const float* W_r0b = Wf + off[9],  *B_r0b = Wf + off[10];
    const float* W_r1a = Wf + off[11], *B_r1a = Wf + off[12];
    const float* W_r1b = Wf + off[13], *B_r1b = Wf + off[14];
    const float* W_qc  = Wf + off[15], *B_qc  = Wf + off[16];
    const float* Emb   = Wf + off[17];
    const float* W_d0  = Wf + off[18], *B_d0  = Wf + off[19];
    const float* W_s0a = Wf + off[20], *B_s0a = Wf + off[21];
    const float* W_s0b = Wf + off[22], *B_s0b = Wf + off[23];
    const float* W_s1a = Wf + off[24], *B_s1a = Wf + off[25];
    const float* W_s1b = Wf + off[26], *B_s1b = Wf + off[27];
    const float* W_d1  = Wf + off[28], *B_d1  = Wf + off[29];
    const float* W_d2  = Wf + off[30], *B_d2  = Wf + off[31];

    dim3 blk(256);
    auto g = [MCr](int o) { return dim3(MCr / 128, (o + 63) / 64); };
    const float* nf = nullptr;

    detect_k<<<1, blk, 0, stream>>>(d_in[0], dtf, acc);
    convw_k<<<31, blk, 0, stream>>>(t, Wf, dtf);
    prep_k<<<128, blk, 0, stream>>>(Emb, Et);
    e2_k<<<2, blk, 0, stream>>>(Et, e2);

    // ---- encoder (chunked); qc writes straight into Zq slice ----
    for (int c = 0; c < NC; ++c) {
        const size_t r0 = (size_t)c * MCr;
        gemm_k<false, true,  false, 2, 0><<<g(128), blk, 0, stream>>>(d_in[0], r0 * 165, W_ew0, B_ew0, nf, A1, 0, MCr, 165, 128, dtf);
        gemm_k<false, true,  false, 0, 0><<<g(256), blk, 0, stream>>>(A1, 0, W_ew1, B_ew1, nf, A2, 0, MCr, 128, 256, dtf);
        gemm_k<false, false, false, 0, 0><<<g(256), blk, 0, stream>>>(A2, 0, W_ew2, B_ew2, nf, A1, 0, MCr, 256, 256, dtf);
        gemm_k<true,  true,  false, 0, 0><<<g(32),  blk, 0, stream>>>(A1, 0, W_r0a, B_r0a, nf, A2, 0, MCr, 256, 32, dtf);
        gemm_k<false, false, true,  0, 0><<<g(256), blk, 0, stream>>>(A2, 0, W_r0b, B_r0b, A1, A1, 0, MCr, 32, 256, dtf);
        gemm_k<true,  true,  false, 0, 0><<<g(32),  blk, 0, stream>>>(A1, 0, W_r1a, B_r1a, nf, A2, 0, MCr, 256, 32, dtf);
        gemm_k<false, false, true,  0, 0><<<g(256), blk, 0, stream>>>(A2, 0, W_r1b, B_r1b, A1, A1, 0, MCr, 32, 256, dtf);
        gemm_k<true,  false, false, 0, 0><<<g(64),  blk, 0, stream>>>(A1, 0, W_qc,  B_qc,  nf, Zq, r0 * 64, MCr, 256, 64, dtf);
    }

    // ---- VQ over full N, in place ----
    vq_k<<<NTOT / 64, blk, 0, stream>>>(Zq, Et, e2, acc);

    // ---- decoder (chunked) ----
    for (int c = 0; c < NC; ++c) {
        const size_t r0 = (size_t)c * MCr;
        gemm_k<false, false, false, 0, 0><<<g(256), blk, 0, stream>>>(Zq, r0 * 64, W_d0, B_d0, nf, A1, 0, MCr, 64, 256, dtf);
        gemm_k<true,  true,  false, 0, 0><<<g(32),  blk, 0, stream>>>(A1, 0, W_s0a, B_s0a, nf, A2, 0, MCr, 256, 32, dtf);
        gemm_k<false, false, true,  0, 0><<<g(256), blk, 0, stream>>>(A2, 0, W_s0b, B_s0b, A1, A1, 0, MCr, 32, 256, dtf);
        gemm_k<true,  true,  false, 0, 0><<<g(32),  blk, 0, stream>>>(A1, 0, W_s1a, B_s1a, nf, A2, 0, MCr, 256, 32, dtf);
        gemm_k<false, false, true,  0, 0><<<g(256), blk, 0, stream>>>(A2, 0, W_s1b, B_s1b, A1, A1, 0, MCr, 32, 256, dtf);
        gemm_k<true,  true,  false, 0, 0><<<g(128), blk, 0, stream>>>(A1, 0, W_d1,  B_d1,  nf, A2, 0, MCr, 256, 128, dtf);
        gemm_k<false, false, false, 0, 1><<<g(165), blk, 0, stream>>>(A2, 0, W_d2,  B_d2,  nf, d_out, r0 * 165, MCr, 128, 165, dtf);
    }

    diff_k<<<1, 64, 0, stream>>>(acc, d_out, (size_t)NTOT * 165, dtf);
}

// Round 5
// 2677.582 us; speedup vs baseline: 1.3197x; 1.2031x over previous
//
#include <hip/hip_runtime.h>
#include <hip/hip_bf16.h>

// ---------------------------------------------------------------------------
// VQ-VAE pose: 15 pointwise GEMMs + VQ + MSE. fp32 compute (inputs are fp32).
// Round 5:
//  - vq_k: back to wave-uniform Et scan (scalar-cache broadcast; r4's
//    lane-split caused 16.8 GB of L2 vector reads = the 558 us), but at
//    full N: 512 blocks = 2 waves/SIMD, 2-code ILP. In-place Z->Q.
//  - NC=8 (67.6 MB layout; ws proven >= 69.4 MB by round 3).
//  - SMALL 32x32 GEMM tile for O<=64 layers (they had 64-128 blocks only).
// ---------------------------------------------------------------------------

#define NTOT 131072            // B*T
#define EDIM 64
#define NEMB 512

// ---------------- dtype detection (fp32 vs bf16) ---------------------------
__global__ void detect_k(const void* __restrict__ x, int* __restrict__ flag,
                         float* __restrict__ acc)
{
    __shared__ int s_bad;
    if (threadIdx.x == 0) s_bad = 0;
    __syncthreads();
    const unsigned short* u = (const unsigned short*)x;
    int bad = 0;
    for (int i = threadIdx.x; i < 2048; i += 256) {
        unsigned short h = u[i];
        int ex = (h >> 7) & 0xFF;
        if (h != 0 && (ex < 100 || ex > 140)) bad++;
    }
    atomicAdd(&s_bad, bad);
    __syncthreads();
    if (threadIdx.x == 0) { *flag = (s_bad > 256) ? 1 : 0; *acc = 0.f; }
}

// ---------------- convert weights/biases/embed to fp32 ---------------------
struct WTbl { const void* p[31]; int off[31]; int n[31]; };

__global__ void convw_k(WTbl t, float* __restrict__ dst, const int* __restrict__ flag)
{
    const bool f32 = (*flag != 0);
    const int ti = blockIdx.x;
    const void* src = t.p[ti];
    float* d = dst + t.off[ti];
    const int n = t.n[ti];
    for (int i = threadIdx.x; i < n; i += 256)
        d[i] = f32 ? ((const float*)src)[i]
                   : __bfloat162float(((const __hip_bfloat16*)src)[i]);
}

// ---------------- GEMM ------------------------------------------------------
// Y[M,O] = act((PRE?relu(X):X)[M,K] @ W[O,K]^T + b) (+R).
// Tile MT x NT, BK=32, 256 threads. BIG=128x64 (8x4/thr), SMALL=32x32 (1x4).
// XM: 0=fp32 buffer, 2=dynamic (d_in[0]).  YM: 0=fp32 buffer, 1=dynamic (d_out).
template <int XM>
static __device__ __forceinline__ float ldx(const void* p, size_t i, bool f32d)
{
    if (XM == 0) return ((const float*)p)[i];
    return f32d ? ((const float*)p)[i]
                : __bfloat162float(((const __hip_bfloat16*)p)[i]);
}

template <int MT, int NT, bool PRE_RELU, bool POST_RELU, bool RES, int XM, int YM>
__global__ __launch_bounds__(256)
void gemm_k(const void* __restrict__ X, size_t xoff,
            const float* __restrict__ W, const float* __restrict__ Bv,
            const float* __restrict__ R, void* __restrict__ Y, size_t yoff,
            int M, int K, int O, const int* __restrict__ dtf)
{
    __shared__ float Xs[32][MT + 4];
    __shared__ float Ws[32][NT + 4];

    constexpr int TXN  = NT / 4;             // thread-groups across cols
    constexpr int ROWS = (MT * NT) / 1024;   // rows per thread

    const bool f32d = (XM == 2 || YM == 1) ? (*dtf != 0) : false;

    const int tid = threadIdx.x;
    const int tx  = tid & (TXN - 1);
    const int ty  = tid / TXN;
    const int m0  = blockIdx.x * MT;
    const int o0  = blockIdx.y * NT;

    float acc[ROWS][4] = {};

    const int KC = (K + 31) >> 5;
    for (int kc = 0; kc < KC; ++kc) {
        const int k0 = kc << 5;
        // ---- stage X (MT x 32), pre-ReLU fused ----
        if (XM == 0 && (K & 3) == 0) {
            #pragma unroll
            for (int it = 0; it < MT * 8 / 256; ++it) {
                int idx = tid + it * 256;
                int kq = idx & 7, m = idx >> 3;
                int kg = k0 + kq * 4;
                float4 v = make_float4(0.f, 0.f, 0.f, 0.f);
                if (kg < K)
                    v = *(const float4*)((const float*)X + xoff + (size_t)(m0 + m) * K + kg);
                if (PRE_RELU) {
                    v.x = fmaxf(v.x, 0.f); v.y = fmaxf(v.y, 0.f);
                    v.z = fmaxf(v.z, 0.f); v.w = fmaxf(v.w, 0.f);
                }
                Xs[kq * 4 + 0][m] = v.x; Xs[kq * 4 + 1][m] = v.y;
                Xs[kq * 4 + 2][m] = v.z; Xs[kq * 4 + 3][m] = v.w;
            }
        } else {
            #pragma unroll
            for (int it = 0; it < MT * 32 / 256; ++it) {
                int e = tid + it * 256;
                int kk = e & 31, m = e >> 5;
                int kg = k0 + kk;
                float v = 0.f;
                if (kg < K) v = ldx<XM>(X, xoff + (size_t)(m0 + m) * K + kg, f32d);
                if (PRE_RELU) v = fmaxf(v, 0.f);
                Xs[kk][m] = v;
            }
        }
        // ---- stage W (NT x 32) ----
        if ((K & 3) == 0) {
            #pragma unroll
            for (int it = 0; it < NT * 8 / 256; ++it) {
                int idx = tid + it * 256;
                int kq = idx & 7, o = idx >> 3;
                int kg = k0 + kq * 4, og = o0 + o;
                float4 v = make_float4(0.f, 0.f, 0.f, 0.f);
                if (kg < K && og < O)
                    v = *(const float4*)(W + (size_t)og * K + kg);
                Ws[kq * 4 + 0][o] = v.x; Ws[kq * 4 + 1][o] = v.y;
                Ws[kq * 4 + 2][o] = v.z; Ws[kq * 4 + 3][o] = v.w;
            }
        } else {
            #pragma unroll
            for (int it = 0; it < NT * 32 / 256; ++it) {
                int e = tid + it * 256;
                int kk = e & 31, o = e >> 5;
                int kg = k0 + kk, og = o0 + o;
                Ws[kk][o] = (kg < K && og < O) ? W[(size_t)og * K + kg] : 0.f;
            }
        }
        __syncthreads();
        // ---- compute ----
        #pragma unroll
        for (int kk = 0; kk < 32; ++kk) {
            float a[ROWS], b[4];
            *(float4*)&b[0] = *(const float4*)&Ws[kk][tx * 4];
            if (ROWS == 8) {
                *(float4*)&a[0] = *(const float4*)&Xs[kk][ty * 8];
                *(float4*)&a[4] = *(const float4*)&Xs[kk][ty * 8 + 4];
            } else {
                a[0] = Xs[kk][ty];
            }
            #pragma unroll
            for (int i = 0; i < ROWS; ++i)
                #pragma unroll
                for (int j = 0; j < 4; ++j)
                    acc[i][j] = fmaf(a[i], b[j], acc[i][j]);
        }
        __syncthreads();
    }

    // ---- epilogue ----
    if (YM == 0 && (o0 + NT <= O)) {
        const int c0 = o0 + tx * 4;
        float4 bb = *(const float4*)(Bv + c0);
        #pragma unroll
        for (int i = 0; i < ROWS; ++i) {
            int r = m0 + ty * ROWS + i;
            float4 v;
            v.x = acc[i][0] + bb.x; v.y = acc[i][1] + bb.y;
            v.z = acc[i][2] + bb.z; v.w = acc[i][3] + bb.w;
            if (RES) {
                float4 rv = *(const float4*)(R + (size_t)r * O + c0);
                v.x += rv.x; v.y += rv.y; v.z += rv.z; v.w += rv.w;
            }
            if (POST_RELU) {
                v.x = fmaxf(v.x, 0.f); v.y = fmaxf(v.y, 0.f);
                v.z = fmaxf(v.z, 0.f); v.w = fmaxf(v.w, 0.f);
            }
            *(float4*)((float*)Y + yoff + (size_t)r * O + c0) = v;
        }
    } else {
        #pragma unroll
        for (int j = 0; j < 4; ++j) {
            int c = o0 + tx * 4 + j;
            if (c >= O) continue;
            float bb = Bv[c];
            #pragma unroll
            for (int i = 0; i < ROWS; ++i) {
                int r = m0 + ty * ROWS + i;
                float v = acc[i][j] + bb;
                if (RES) v += R[(size_t)r * O + c];
                if (POST_RELU) v = fmaxf(v, 0.f);
                size_t yi = yoff + (size_t)r * O + c;
                if (YM == 0)   ((float*)Y)[yi] = v;
                else if (f32d) ((float*)Y)[yi] = v;
                else           ((__hip_bfloat16*)Y)[yi] = __float2bfloat16(v);
            }
        }
    }
}

// ---------------- codebook prep --------------------------------------------
__global__ void prep_k(const float* __restrict__ E, float* __restrict__ Et)
{
    int idx = blockIdx.x * 256 + threadIdx.x;   // E is [64][512]
    Et[(idx & 511) * EDIM + (idx >> 9)] = E[idx];
}

__global__ void e2_k(const float* __restrict__ Et, float* __restrict__ e2)
{
    int e = blockIdx.x * 256 + threadIdx.x;
    float s = 0.f;
    #pragma unroll
    for (int d = 0; d < EDIM; ++d) { float v = Et[e * EDIM + d]; s = fmaf(v, v, s); }
    e2[e] = s;
}

// ---------------- VQ: one thread per row, wave-uniform code scan -----------
// Et addresses are uniform (loop-counter based) -> scalar loads broadcast via
// the constant cache: no per-lane vector traffic (r4's mistake).
__global__ __launch_bounds__(256)
void vq_k(float* __restrict__ Zq, const float* __restrict__ Et,
          const float* __restrict__ e2, float* __restrict__ acc)
{
    const int r = blockIdx.x * 256 + threadIdx.x;   // 512 blocks -> 131072 rows
    float z[64];
    float* zp = Zq + (size_t)r * 64;
    #pragma unroll
    for (int d4 = 0; d4 < 16; ++d4)
        *(float4*)&z[d4 * 4] = *(const float4*)(zp + d4 * 4);

    float best = 3.4e38f;
    int   bi   = 0;
    for (int e = 0; e < NEMB; e += 2) {
        const float* er0 = Et + (size_t)e * 64;
        const float* er1 = er0 + 64;
        float d0 = 0.f, d1 = 0.f;
        #pragma unroll
        for (int d = 0; d < 64; ++d) {
            d0 = fmaf(z[d], er0[d], d0);
            d1 = fmaf(z[d], er1[d], d1);
        }
        float s0 = fmaf(-2.f, d0, e2[e]);
        float s1 = fmaf(-2.f, d1, e2[e + 1]);
        if (s0 < best) { best = s0; bi = e; }       // ascending: first-min = np
        if (s1 < best) { best = s1; bi = e + 1; }
    }

    const float* eb = Et + (size_t)bi * 64;
    float ds = 0.f;
    #pragma unroll
    for (int d4 = 0; d4 < 16; ++d4) {
        float4 qv = *(const float4*)(eb + d4 * 4);
        float t;
        t = qv.x - z[d4 * 4 + 0]; ds = fmaf(t, t, ds);
        t = qv.y - z[d4 * 4 + 1]; ds = fmaf(t, t, ds);
        t = qv.z - z[d4 * 4 + 2]; ds = fmaf(t, t, ds);
        t = qv.w - z[d4 * 4 + 3]; ds = fmaf(t, t, ds);
        *(float4*)(zp + d4 * 4) = qv;               // in-place Z -> Q
    }
    #pragma unroll
    for (int off = 32; off; off >>= 1) ds += __shfl_down(ds, off);
    if ((threadIdx.x & 63) == 0) atomicAdd(acc, ds);
}

__global__ void diff_k(const float* __restrict__ acc, void* __restrict__ out,
                       size_t off, const int* __restrict__ dtf)
{
    if (threadIdx.x == 0) {
        float v = *acc * (1.0f / 8388608.0f);   // /(32*4096*64)
        if (*dtf) ((float*)out)[off] = v;
        else      ((__hip_bfloat16*)out)[off] = __float2bfloat16(v);
    }
}

// ---------------------------------------------------------------------------
extern "C" void kernel_launch(void* const* d_in, const int* in_sizes, int n_in,
                              void* d_out, int out_size, void* d_ws, size_t ws_size,
                              hipStream_t stream)
{
    // ---- runtime chunk count (need: 32MB Zq + 2*S + ~3MB) ----
    int NC;
    const size_t MB = 1048576;
    if      (ws_size >= 304 * MB) NC = 1;
    else if (ws_size >= 172 * MB) NC = 2;
    else if (ws_size >= 102 * MB) NC = 4;
    else if (ws_size >= 69  * MB + 512 * 1024) NC = 8;   // 67.6 MB actual need
    else                          NC = 16;
    const int MCr = NTOT / NC;
    const size_t S = (size_t)MCr * 256 * 4;

    char* ws = (char*)d_ws;
    float* Zq  = (float*)ws;                         // N x 64 fp32 (32 MiB)
    float* A1  = (float*)(ws + 32 * MB);
    float* A2  = (float*)(ws + 32 * MB + S);
    float* Wf  = (float*)(ws + 32 * MB + 2 * S);
    float* Et  = (float*)(ws + 32 * MB + 2 * S + 2 * MB);
    float* e2  = Et + NEMB * EDIM;
    float* acc = e2 + NEMB;
    int*   dtf = (int*)(acc + 1);

    WTbl t;
    int off[32];
    int cum = 0;
    for (int i = 1; i < 32; ++i) {
        t.p[i - 1]   = d_in[i];
        t.off[i - 1] = cum;
        t.n[i - 1]   = in_sizes[i];
        off[i] = cum;
        cum += in_sizes[i];
    }
    const float* W_ew0 = Wf + off[1],  *B_ew0 = Wf + off[2];
    const float* W_ew1 = Wf + off[3],  *B_ew1 = Wf + off[4];
    const float* W_ew2 = Wf + off[5],  *B_ew2 = Wf + off[6];
    const float* W_r0a = Wf + off[7],  *B_r0a = Wf + off[8];
    const float* W_r0b = Wf + off[9],  *B_r0b = Wf + off[10];
    const float* W_r1a = Wf + off[11], *B_r1a = Wf + off[12];
    const float* W_r1b = Wf + off[13], *B_r1b = Wf + off[14];
    const float* W_qc  = Wf + off[15], *B_qc  = Wf + off[16];
    const float* Emb   = Wf + off[17];
    const float* W_d0  = Wf + off[18], *B_d0  = Wf + off[19];
    const float* W_s0a = Wf + off[20], *B_s0a = Wf + off[21];
    const float* W_s0b = Wf + off[22], *B_s0b = Wf + off[23];
    const float* W_s1a = Wf + off[24], *B_s1a = Wf + off[25];
    const float* W_s1b = Wf + off[26], *B_s1b = Wf + off[27];
    const float* W_d1  = Wf + off[28], *B_d1  = Wf + off[29];
    const float* W_d2  = Wf + off[30], *B_d2  = Wf + off[31];

    dim3 blk(256);
    auto gB = [MCr](int o) { return dim3(MCr / 128, (o + 63) / 64); };  // BIG
    auto gS = [MCr](int o) { return dim3(MCr / 32,  (o + 31) / 32); };  // SMALL
    const float* nf = nullptr;

    detect_k<<<1, blk, 0, stream>>>(d_in[0], dtf, acc);
    convw_k<<<31, blk, 0, stream>>>(t, Wf, dtf);
    prep_k<<<128, blk, 0, stream>>>(Emb, Et);
    e2_k<<<2, blk, 0, stream>>>(Et, e2);

    // ---- encoder (chunked); qc writes straight into Zq slice ----
    for (int c = 0; c < NC; ++c) {
        const size_t r0 = (size_t)c * MCr;
        gemm_k<128,64, false,true, false, 2,0><<<gB(128), blk, 0, stream>>>(d_in[0], r0*165, W_ew0, B_ew0, nf, A1, 0, MCr, 165, 128, dtf);
        gemm_k<128,64, false,true, false, 0,0><<<gB(256), blk, 0, stream>>>(A1, 0, W_ew1, B_ew1, nf, A2, 0, MCr, 128, 256, dtf);
        gemm_k<128,64, false,false,false, 0,0><<<gB(256), blk, 0, stream>>>(A2, 0, W_ew2, B_ew2, nf, A1, 0, MCr, 256, 256, dtf);
        gemm_k<32,32,  true, true, false, 0,0><<<gS(32),  blk, 0, stream>>>(A1, 0, W_r0a, B_r0a, nf, A2, 0, MCr, 256, 32, dtf);
        gemm_k<128,64, false,false,true,  0,0><<<gB(256), blk, 0, stream>>>(A2, 0, W_r0b, B_r0b, A1, A1, 0, MCr, 32, 256, dtf);
        gemm_k<32,32,  true, true, false, 0,0><<<gS(32),  blk, 0, stream>>>(A1, 0, W_r1a, B_r1a, nf, A2, 0, MCr, 256, 32, dtf);
        gemm_k<128,64, false,false,true,  0,0><<<gB(256), blk, 0, stream>>>(A2, 0, W_r1b, B_r1b, A1, A1, 0, MCr, 32, 256, dtf);
        gemm_k<32,32,  true, false,false, 0,0><<<gS(64),  blk, 0, stream>>>(A1, 0, W_qc,  B_qc,  nf, Zq, r0*64, MCr, 256, 64, dtf);
    }

    // ---- VQ over full N, in place ----
    vq_k<<<NTOT / 256, blk, 0, stream>>>(Zq, Et, e2, acc);

    // ---- decoder (chunked) ----
    for (int c = 0; c < NC; ++c) {
        const size_t r0 = (size_t)c * MCr;
        gemm_k<128,64, false,false,false, 0,0><<<gB(256), blk, 0, stream>>>(Zq, r0*64, W_d0, B_d0, nf, A1, 0, MCr, 64, 256, dtf);
        gemm_k<32,32,  true, true, false, 0,0><<<gS(32),  blk, 0, stream>>>(A1, 0, W_s0a, B_s0a, nf, A2, 0, MCr, 256, 32, dtf);
        gemm_k<128,64, false,false,true,  0,0><<<gB(256), blk, 0, stream>>>(A2, 0, W_s0b, B_s0b, A1, A1, 0, MCr, 32, 256, dtf);
        gemm_k<32,32,  true, true, false, 0,0><<<gS(32),  blk, 0, stream>>>(A1, 0, W_s1a, B_s1a, nf, A2, 0, MCr, 256, 32, dtf);
        gemm_k<128,64, false,false,true,  0,0><<<gB(256), blk, 0, stream>>>(A2, 0, W_s1b, B_s1b, A1, A1, 0, MCr, 32, 256, dtf);
        gemm_k<128,64, true, true, false, 0,0><<<gB(128), blk, 0, stream>>>(A1, 0, W_d1,  B_d1,  nf, A2, 0, MCr, 256, 128, dtf);
        gemm_k<128,64, false,false,false, 0,1><<<gB(165), blk, 0, stream>>>(A2, 0, W_d2,  B_d2,  nf, d_out, r0*165, MCr, 128, 165, dtf);
    }

    diff_k<<<1, 64, 0, stream>>>(acc, d_out, (size_t)NTOT * 165, dtf);
}

// Round 6
// 2617.003 us; speedup vs baseline: 1.3503x; 1.0231x over previous
//
#include <hip/hip_runtime.h>
#include <hip/hip_bf16.h>

// ---------------------------------------------------------------------------
// VQ-VAE pose: fused fp32 pipeline. Round 6:
//  - fused enc0+enc1 kernel, fused resblock kernel (x4, in-place),
//  - standalone gemms with swizzled grid (col-block fastest -> L2 X reuse),
//  - weights transposed to K-major at convert time (wave-uniform s_loads),
//  - NC=1 proven by round-5 counters (ws >= 304 MB); chunking removed.
// ---------------------------------------------------------------------------

#define NTOT 131072            // B*T
#define EDIM 64
#define NEMB 512

// ---------------- dtype detection (fp32 vs bf16) ---------------------------
__global__ void detect_k(const void* __restrict__ x, int* __restrict__ flag,
                         float* __restrict__ acc)
{
    __shared__ int s_bad;
    if (threadIdx.x == 0) s_bad = 0;
    __syncthreads();
    const unsigned short* u = (const unsigned short*)x;
    int bad = 0;
    for (int i = threadIdx.x; i < 2048; i += 256) {
        unsigned short h = u[i];
        int ex = (h >> 7) & 0xFF;
        if (h != 0 && (ex < 100 || ex > 140)) bad++;
    }
    atomicAdd(&s_bad, bad);
    __syncthreads();
    if (threadIdx.x == 0) { *flag = (s_bad > 256) ? 1 : 0; *acc = 0.f; }
}

// -------- convert weights to fp32; 2-D weights transposed to K-major -------
struct WTbl { const void* p[31]; int off[31]; int n[31]; int Kd[31]; };

__global__ void convw_k(WTbl t, float* __restrict__ dst, const int* __restrict__ flag)
{
    const bool f32 = (*flag != 0);
    const int ti = blockIdx.x;
    const void* src = t.p[ti];
    float* d = dst + t.off[ti];
    const int n = t.n[ti];
    const int K = t.Kd[ti];
    if (K == 0) {
        for (int i = threadIdx.x; i < n; i += 256)
            d[i] = f32 ? ((const float*)src)[i]
                       : __bfloat162float(((const __hip_bfloat16*)src)[i]);
    } else {
        const int O = n / K;
        for (int j = threadIdx.x; j < n; j += 256) {
            int k = j / O, o = j - k * O;           // dst[k][o] = src[o][k]
            int si = o * K + k;
            d[j] = f32 ? ((const float*)src)[si]
                       : __bfloat162float(((const __hip_bfloat16*)src)[si]);
        }
    }
}

// ---------------- fused enc0+enc1: x[165] -> relu128 -> relu256 ------------
__global__ __launch_bounds__(256)
void enc01_k(const void* __restrict__ X,
             const float* __restrict__ W0t, const float* __restrict__ B0,  // [165][128],[128]
             const float* __restrict__ W1t, const float* __restrict__ B1,  // [128][256],[256]
             float* __restrict__ Y, const int* __restrict__ dtf)
{
    __shared__ float Xs[32][64];     // k-major chunk: conflict-free lane reads
    __shared__ float H1[64][131];    // 128 cols + 3 pad (stride 131 -> 2-way, free)
    const bool f32d = (*dtf != 0);
    const int tid = threadIdx.x;
    const int r0  = blockIdx.x * 64;
    const int r   = tid & 63;
    const int w   = __builtin_amdgcn_readfirstlane(tid >> 6);   // wave id 0..3

    float acc[32] = {};
    for (int kc = 0; kc < 6; ++kc) {             // 6*32 = 192 >= 165
        const int k0 = kc * 32;
        #pragma unroll
        for (int it = 0; it < 8; ++it) {
            int e = tid + it * 256;              // 2048 = 64 rows x 32 k
            int kk = e & 31, m = e >> 5;
            int kg = k0 + kk;
            float v = 0.f;
            if (kg < 165) {
                size_t idx = (size_t)(r0 + m) * 165 + kg;
                v = f32d ? ((const float*)X)[idx]
                         : __bfloat162float(((const __hip_bfloat16*)X)[idx]);
            }
            Xs[kk][m] = v;
        }
        __syncthreads();
        #pragma unroll
        for (int kk = 0; kk < 32; ++kk) {
            float a = Xs[kk][r];
            const float* wp = W0t + (size_t)min(k0 + kk, 164) * 128 + w * 32;
            #pragma unroll
            for (int j = 0; j < 32; ++j)
                acc[j] = fmaf(a, wp[j], acc[j]);
        }
        __syncthreads();
    }
    #pragma unroll
    for (int j = 0; j < 32; ++j)
        H1[r][w * 32 + j] = fmaxf(acc[j] + B0[w * 32 + j], 0.f);
    __syncthreads();

    // layer 2: K=128 -> 256 cols (4 chunks of 16 per wave), relu, store
    #pragma unroll
    for (int c = 0; c < 4; ++c) {
        const int col0 = w * 64 + c * 16;
        float a2[16] = {};
        for (int k = 0; k < 128; ++k) {
            float tv = H1[r][k];
            const float* wp = W1t + (size_t)k * 256 + col0;
            #pragma unroll
            for (int j = 0; j < 16; ++j)
                a2[j] = fmaf(tv, wp[j], a2[j]);
        }
        float* out = Y + (size_t)(r0 + r) * 256 + col0;
        #pragma unroll
        for (int j = 0; j < 16; ++j)
            out[j] = fmaxf(a2[j] + B1[col0 + j], 0.f);
    }
}

// ---------------- fused resblock: h += W1 @ relu(W0 @ relu(h)) -------------
// In-place on H (each block owns its 64 rows; residual read is L2-hot).
__global__ __launch_bounds__(256)
void res_k(float* __restrict__ H,
           const float* __restrict__ W0t, const float* __restrict__ B0,  // [256][32],[32]
           const float* __restrict__ W1t, const float* __restrict__ B1)  // [32][256],[256]
{
    __shared__ float Hs[32][64];     // k-major chunk of relu(h)
    __shared__ float T1[64][33];     // mid activations (stride 33 -> free)
    const int tid = threadIdx.x;
    const int r0  = blockIdx.x * 64;
    const int r   = tid & 63;
    const int w   = __builtin_amdgcn_readfirstlane(tid >> 6);

    float acc[8] = {};
    for (int kc = 0; kc < 8; ++kc) {             // K=256
        const int k0 = kc * 32;
        #pragma unroll
        for (int it = 0; it < 8; ++it) {
            int e = tid + it * 256;
            int kk = e & 31, m = e >> 5;
            Hs[kk][m] = fmaxf(H[(size_t)(r0 + m) * 256 + k0 + kk], 0.f);
        }
        __syncthreads();
        #pragma unroll
        for (int kk = 0; kk < 32; ++kk) {
            float a = Hs[kk][r];
            const float* wp = W0t + (size_t)(k0 + kk) * 32 + w * 8;
            #pragma unroll
            for (int j = 0; j < 8; ++j)
                acc[j] = fmaf(a, wp[j], acc[j]);
        }
        __syncthreads();
    }
    #pragma unroll
    for (int j = 0; j < 8; ++j)
        T1[r][w * 8 + j] = fmaxf(acc[j] + B0[w * 8 + j], 0.f);
    __syncthreads();

    // mm2: K=32 -> 256 cols; add residual (in-place) + bias
    #pragma unroll
    for (int c = 0; c < 4; ++c) {
        const int col0 = w * 64 + c * 16;
        float a2[16] = {};
        #pragma unroll
        for (int k = 0; k < 32; ++k) {
            float tv = T1[r][k];
            const float* wp = W1t + (size_t)k * 256 + col0;
            #pragma unroll
            for (int j = 0; j < 16; ++j)
                a2[j] = fmaf(tv, wp[j], a2[j]);
        }
        float* out = H + (size_t)(r0 + r) * 256 + col0;
        #pragma unroll
        for (int j = 0; j < 16; ++j)
            out[j] = out[j] + a2[j] + B1[col0 + j];
    }
}

// ---------------- standalone GEMM (fp32 X, K-major W, swizzled grid) -------
// grid = (ceil(O/64), M/128): col-block fastest -> concurrent blocks share X.
template <bool PRE_RELU, bool POST_RELU, int YM>
__global__ __launch_bounds__(256)
void gemm_k(const float* __restrict__ X, const float* __restrict__ Wt,
            const float* __restrict__ Bv, void* __restrict__ Y,
            int K, int O, const int* __restrict__ dtf)
{
    __shared__ float Xs[32][132];
    __shared__ float Ws[32][68];

    const bool f32d = (YM == 1) ? (*dtf != 0) : false;
    const int tid = threadIdx.x;
    const int tx  = tid & 15;
    const int ty  = tid >> 4;
    const int o0  = blockIdx.x * 64;
    const int m0  = blockIdx.y * 128;

    float acc[8][4] = {};
    const int KC = K >> 5;                       // K multiple of 32
    for (int kc = 0; kc < KC; ++kc) {
        const int k0 = kc << 5;
        #pragma unroll
        for (int it = 0; it < 4; ++it) {         // X: 128 x 32 as float4
            int idx = tid + it * 256;
            int kq = idx & 7, m = idx >> 3;
            float4 v = *(const float4*)(X + (size_t)(m0 + m) * K + k0 + kq * 4);
            if (PRE_RELU) {
                v.x = fmaxf(v.x, 0.f); v.y = fmaxf(v.y, 0.f);
                v.z = fmaxf(v.z, 0.f); v.w = fmaxf(v.w, 0.f);
            }
            Xs[kq * 4 + 0][m] = v.x; Xs[kq * 4 + 1][m] = v.y;
            Xs[kq * 4 + 2][m] = v.z; Xs[kq * 4 + 3][m] = v.w;
        }
        if ((O & 3) == 0) {                      // W: 32 x 64, K-major direct
            #pragma unroll
            for (int it = 0; it < 2; ++it) {
                int idx = tid + it * 256;
                int oq = idx & 15, kk = idx >> 4;
                float4 v = make_float4(0.f, 0.f, 0.f, 0.f);
                if (o0 + oq * 4 < O)
                    v = *(const float4*)(Wt + (size_t)(k0 + kk) * O + o0 + oq * 4);
                *(float4*)&Ws[kk][oq * 4] = v;
            }
        } else {
            #pragma unroll
            for (int it = 0; it < 8; ++it) {
                int e = tid + it * 256;
                int kk = e & 31, o = e >> 5;
                int og = o0 + o;
                Ws[kk][o] = (og < O) ? Wt[(size_t)(k0 + kk) * O + og] : 0.f;
            }
        }
        __syncthreads();
        #pragma unroll
        for (int kk = 0; kk < 32; ++kk) {
            float a[8], b[4];
            *(float4*)&a[0] = *(const float4*)&Xs[kk][ty * 8];
            *(float4*)&a[4] = *(const float4*)&Xs[kk][ty * 8 + 4];
            *(float4*)&b[0] = *(const float4*)&Ws[kk][tx * 4];
            #pragma unroll
            for (int i = 0; i < 8; ++i)
                #pragma unroll
                for (int j = 0; j < 4; ++j)
                    acc[i][j] = fmaf(a[i], b[j], acc[i][j]);
        }
        __syncthreads();
    }

    if (YM == 0 && (O & 63) == 0) {
        const int c0 = o0 + tx * 4;
        float4 bb = *(const float4*)(Bv + c0);
        #pragma unroll
        for (int i = 0; i < 8; ++i) {
            int r = m0 + ty * 8 + i;
            float4 v;
            v.x = acc[i][0] + bb.x; v.y = acc[i][1] + bb.y;
            v.z = acc[i][2] + bb.z; v.w = acc[i][3] + bb.w;
            if (POST_RELU) {
                v.x = fmaxf(v.x, 0.f); v.y = fmaxf(v.y, 0.f);
                v.z = fmaxf(v.z, 0.f); v.w = fmaxf(v.w, 0.f);
            }
            *(float4*)((float*)Y + (size_t)r * O + c0) = v;
        }
    } else {
        #pragma unroll
        for (int j = 0; j < 4; ++j) {
            int c = o0 + tx * 4 + j;
            if (c >= O) continue;
            float bb = Bv[c];
            #pragma unroll
            for (int i = 0; i < 8; ++i) {
                int r = m0 + ty * 8 + i;
                float v = acc[i][j] + bb;
                if (POST_RELU) v = fmaxf(v, 0.f);
                size_t yi = (size_t)r * O + c;
                if (YM == 0)   ((float*)Y)[yi] = v;
                else if (f32d) ((float*)Y)[yi] = v;
                else           ((__hip_bfloat16*)Y)[yi] = __float2bfloat16(v);
            }
        }
    }
}

// ---------------- codebook prep --------------------------------------------
__global__ void prep_k(const float* __restrict__ E, float* __restrict__ Et)
{
    int idx = blockIdx.x * 256 + threadIdx.x;   // E is [64][512]
    Et[(idx & 511) * EDIM + (idx >> 9)] = E[idx];
}

__global__ void e2_k(const float* __restrict__ Et, float* __restrict__ e2)
{
    int e = blockIdx.x * 256 + threadIdx.x;
    float s = 0.f;
    #pragma unroll
    for (int d = 0; d < EDIM; ++d) { float v = Et[e * EDIM + d]; s = fmaf(v, v, s); }
    e2[e] = s;
}

// ---------------- VQ: one thread/row, wave-uniform scan, in-place ----------
__global__ __launch_bounds__(256)
void vq_k(float* __restrict__ Zq, const float* __restrict__ Et,
          const float* __restrict__ e2, float* __restrict__ acc)
{
    const int r = blockIdx.x * 256 + threadIdx.x;
    float z[64];
    float* zp = Zq + (size_t)r * 64;
    #pragma unroll
    for (int d4 = 0; d4 < 16; ++d4)
        *(float4*)&z[d4 * 4] = *(const float4*)(zp + d4 * 4);

    float best = 3.4e38f;
    int   bi   = 0;
    for (int e = 0; e < NEMB; e += 2) {
        const float* er0 = Et + (size_t)e * 64;
        const float* er1 = er0 + 64;
        float d0 = 0.f, d1 = 0.f;
        #pragma unroll
        for (int d = 0; d < 64; ++d) {
            d0 = fmaf(z[d], er0[d], d0);
            d1 = fmaf(z[d], er1[d], d1);
        }
        float s0 = fmaf(-2.f, d0, e2[e]);
        float s1 = fmaf(-2.f, d1, e2[e + 1]);
        if (s0 < best) { best = s0; bi = e; }
        if (s1 < best) { best = s1; bi = e + 1; }
    }

    const float* eb = Et + (size_t)bi * 64;
    float ds = 0.f;
    #pragma unroll
    for (int d4 = 0; d4 < 16; ++d4) {
        float4 qv = *(const float4*)(eb + d4 * 4);
        float t;
        t = qv.x - z[d4 * 4 + 0]; ds = fmaf(t, t, ds);
        t = qv.y - z[d4 * 4 + 1]; ds = fmaf(t, t, ds);
        t = qv.z - z[d4 * 4 + 2]; ds = fmaf(t, t, ds);
        t = qv.w - z[d4 * 4 + 3]; ds = fmaf(t, t, ds);
        *(float4*)(zp + d4 * 4) = qv;
    }
    #pragma unroll
    for (int off = 32; off; off >>= 1) ds += __shfl_down(ds, off);
    if ((threadIdx.x & 63) == 0) atomicAdd(acc, ds);
}

__global__ void diff_k(const float* __restrict__ acc, void* __restrict__ out,
                       size_t off, const int* __restrict__ dtf)
{
    if (threadIdx.x == 0) {
        float v = *acc * (1.0f / 8388608.0f);
        if (*dtf) ((float*)out)[off] = v;
        else      ((__hip_bfloat16*)out)[off] = __float2bfloat16(v);
    }
}

// ---------------------------------------------------------------------------
extern "C" void kernel_launch(void* const* d_in, const int* in_sizes, int n_in,
                              void* d_out, int out_size, void* d_ws, size_t ws_size,
                              hipStream_t stream)
{
    const size_t MB = 1048576;
    char* ws = (char*)d_ws;
    float* Zq  = (float*)ws;                                  // N x 64
    float* A1  = (float*)(ws + 32 * MB);                      // N x 256
    float* A2  = (float*)(ws + 32 * MB + 128 * MB);           // N x 256
    float* Wf  = (float*)(ws + 288 * MB);                     // fp32 weights
    float* Et  = (float*)(ws + 288 * MB + 1310720);           // 512 x 64
    float* e2  = Et + NEMB * EDIM;
    float* acc = e2 + NEMB;
    int*   dtf = (int*)(acc + 1);

    // weight table (K-major transpose for 2-D weights)
    static const int KDIM[32] = {0, 165,0, 128,0, 256,0, 256,0, 32,0, 256,0, 32,0,
                                 256,0, 0, 64,0, 256,0, 32,0, 256,0, 32,0, 256,0, 128,0};
    WTbl t;
    int off[32];
    int cum = 0;
    for (int i = 1; i < 32; ++i) {
        t.p[i - 1]   = d_in[i];
        t.off[i - 1] = cum;
        t.n[i - 1]   = in_sizes[i];
        t.Kd[i - 1]  = KDIM[i];
        off[i] = cum;
        cum += in_sizes[i];
    }
    const float* W_ew0 = Wf + off[1],  *B_ew0 = Wf + off[2];
    const float* W_ew1 = Wf + off[3],  *B_ew1 = Wf + off[4];
    const float* W_ew2 = Wf + off[5],  *B_ew2 = Wf + off[6];
    const float* W_r0a = Wf + off[7],  *B_r0a = Wf + off[8];
    const float* W_r0b = Wf + off[9],  *B_r0b = Wf + off[10];
    const float* W_r1a = Wf + off[11], *B_r1a = Wf + off[12];
    const float* W_r1b = Wf + off[13], *B_r1b = Wf + off[14];
    const float* W_qc  = Wf + off[15], *B_qc  = Wf + off[16];
    const float* Emb   = Wf + off[17];
    const float* W_d0  = Wf + off[18], *B_d0  = Wf + off[19];
    const float* W_s0a = Wf + off[20], *B_s0a = Wf + off[21];
    const float* W_s0b = Wf + off[22], *B_s0b = Wf + off[23];
    const float* W_s1a = Wf + off[24], *B_s1a = Wf + off[25];
    const float* W_s1b = Wf + off[26], *B_s1b = Wf + off[27];
    const float* W_d1  = Wf + off[28], *B_d1  = Wf + off[29];
    const float* W_d2  = Wf + off[30], *B_d2  = Wf + off[31];

    dim3 blk(256);
    const int NB = NTOT / 64;          // 2048 row blocks for fused kernels
    auto g = [](int o) { return dim3((o + 63) / 64, NTOT / 128); };  // swizzled

    detect_k<<<1, blk, 0, stream>>>(d_in[0], dtf, acc);
    convw_k<<<31, blk, 0, stream>>>(t, Wf, dtf);
    prep_k<<<128, blk, 0, stream>>>(Emb, Et);
    e2_k<<<2, blk, 0, stream>>>(Et, e2);

    // ---- encoder ----
    enc01_k<<<NB, blk, 0, stream>>>(d_in[0], W_ew0, B_ew0, W_ew1, B_ew1, A1, dtf);
    gemm_k<false, false, 0><<<g(256), blk, 0, stream>>>(A1, W_ew2, B_ew2, A2, 256, 256, dtf);
    res_k<<<NB, blk, 0, stream>>>(A2, W_r0a, B_r0a, W_r0b, B_r0b);
    res_k<<<NB, blk, 0, stream>>>(A2, W_r1a, B_r1a, W_r1b, B_r1b);
    gemm_k<true, false, 0><<<g(64), blk, 0, stream>>>(A2, W_qc, B_qc, Zq, 256, 64, dtf);

    // ---- VQ (in place) ----
    vq_k<<<NTOT / 256, blk, 0, stream>>>(Zq, Et, e2, acc);

    // ---- decoder ----
    gemm_k<false, false, 0><<<g(256), blk, 0, stream>>>(Zq, W_d0, B_d0, A1, 64, 256, dtf);
    res_k<<<NB, blk, 0, stream>>>(A1, W_s0a, B_s0a, W_s0b, B_s0b);
    res_k<<<NB, blk, 0, stream>>>(A1, W_s1a, B_s1a, W_s1b, B_s1b);
    gemm_k<true, true, 0><<<g(128), blk, 0, stream>>>(A1, W_d1, B_d1, A2, 256, 128, dtf);
    gemm_k<false, false, 1><<<g(165), blk, 0, stream>>>(A2, W_d2, B_d2, d_out, 128, 165, dtf);

    diff_k<<<1, 64, 0, stream>>>(acc, d_out, (size_t)NTOT * 165, dtf);
}